// Round 13
// baseline (185.795 us; speedup 1.0000x reference)
//
#include <hip/hip_runtime.h>
#include <hip/hip_bf16.h>

#define IN_CH 64
#define HC 128          // HEADS * OUT_CH
#define HEADS 8
#define OUT_CH 16
#define NEG 0.2f

#define BK_BITS 10
#define BK_SIZE 1024    // nodes per bucket
#define BK_CAP 18432    // padded capacity per bucket (mean 16384, 16-sigma margin)
#define BIN_CHUNK 4096  // edges per b3 block

typedef __attribute__((ext_vector_type(8))) short short8;
typedef __attribute__((ext_vector_type(4))) float f32x4;

__device__ __forceinline__ float lrelu(float x) {
    return fmaxf(x, NEG * x);   // valid for NEG<1
}
__device__ __forceinline__ short f2bf(float f) {
    __hip_bfloat16 b = __float2bfloat16(f);
    return *(short*)&b;
}
__device__ __forceinline__ float bflo(unsigned u) {
    return __uint_as_float(u << 16);
}
__device__ __forceinline__ float bfhi(unsigned u) {
    return __uint_as_float(u & 0xFFFF0000u);
}

// ---- init: bucket cursors + fused attention weights ----
__global__ void init_kernel(const float* __restrict__ W,
                            const float* __restrict__ att_src,
                            const float* __restrict__ att_dst,
                            float* __restrict__ wa,
                            int* __restrict__ cursor, int nbuck)
{
    int t = threadIdx.x;
    if (t < nbuck) cursor[t] = t * BK_CAP;
    for (int idx = t; idx < IN_CH * 16; idx += 256) {
        int k = idx >> 4, i = idx & 15;
        const float* av = (i < 8) ? att_src : att_dst;
        int hd = (i < 8) ? i : i - 8;
        float s = 0.f;
        #pragma unroll
        for (int c = 0; c < 16; ++c)
            s += W[k * HC + hd * 16 + c] * av[hd * 16 + c];
        wa[idx] = s;
    }
}

// ---- projection via MFMA: h = bf16(x) @ bf16(W), logits fused as tile 8 ----
__global__ __launch_bounds__(256) void proj_kernel(
    const float* __restrict__ x, const float* __restrict__ W,
    const float* __restrict__ wa,
    __hip_bfloat16* __restrict__ hb, float* __restrict__ asrc,
    float* __restrict__ adst, int n)
{
    int lane = threadIdx.x & 63;
    int w    = threadIdx.x >> 6;
    int m    = lane & 15;     // A-row / B-col / D-col
    int kg   = lane >> 4;     // k-group

    int rowbase = blockIdx.x * 64 + w * 16;

    short8 bf[9][2];
    #pragma unroll
    for (int s = 0; s < 2; ++s) {
        #pragma unroll
        for (int t = 0; t < 8; ++t) {
            #pragma unroll
            for (int j = 0; j < 8; ++j) {
                int k = s * 32 + kg * 8 + j;
                bf[t][s][j] = f2bf(W[k * HC + t * 16 + m]);
            }
        }
        #pragma unroll
        for (int j = 0; j < 8; ++j) {
            int k = s * 32 + kg * 8 + j;
            bf[8][s][j] = f2bf(wa[k * 16 + m]);
        }
    }

    int rowc = min(rowbase + m, n - 1);
    const float* xp = x + (long long)rowc * IN_CH + kg * 8;
    short8 af[2];
    #pragma unroll
    for (int s = 0; s < 2; ++s) {
        float4 f0 = *(const float4*)(xp + s * 32);
        float4 f1 = *(const float4*)(xp + s * 32 + 4);
        af[s][0] = f2bf(f0.x); af[s][1] = f2bf(f0.y);
        af[s][2] = f2bf(f0.z); af[s][3] = f2bf(f0.w);
        af[s][4] = f2bf(f1.x); af[s][5] = f2bf(f1.y);
        af[s][6] = f2bf(f1.z); af[s][7] = f2bf(f1.w);
    }

    f32x4 acc[9];
    #pragma unroll
    for (int t = 0; t < 9; ++t) acc[t] = (f32x4){0.f, 0.f, 0.f, 0.f};

    #pragma unroll
    for (int s = 0; s < 2; ++s)
        #pragma unroll
        for (int t = 0; t < 9; ++t)
            acc[t] = __builtin_amdgcn_mfma_f32_16x16x32_bf16(
                         af[s], bf[t][s], acc[t], 0, 0, 0);

    #pragma unroll
    for (int r = 0; r < 4; ++r) {
        int orow = rowbase + kg * 4 + r;
        if (orow < n) {
            __hip_bfloat16* hp = hb + (long long)orow * HC + m;
            #pragma unroll
            for (int t = 0; t < 8; ++t)
                hp[t * 16] = __float2bfloat16(acc[t][r]);
            float av = acc[8][r];
            if (m < 8) asrc[orow * HEADS + m] = av;
            else       adst[orow * HEADS + (m - 8)] = av;
        }
    }
}

// ---- bucketed CSR build (fixed-capacity padded buckets) ----
__global__ __launch_bounds__(256) void b3_bin(
    const int* __restrict__ ei, int E, int nbuck,
    int* __restrict__ cursor, unsigned* __restrict__ binned)
{
    __shared__ int cnt[256];
    __shared__ int resv[256];
    int tid = threadIdx.x;
    int chunk0 = blockIdx.x * BIN_CHUNK;
    cnt[tid] = 0;
    __syncthreads();
    for (int i = tid; i < BIN_CHUNK; i += 256) {
        int e = chunk0 + i;
        if (e < E) atomicAdd(&cnt[ei[E + e] >> BK_BITS], 1);
    }
    __syncthreads();
    if (tid < nbuck) resv[tid] = cnt[tid] ? atomicAdd(&cursor[tid], cnt[tid]) : 0;
    __syncthreads();
    for (int i = tid; i < BIN_CHUNK; i += 256) {
        int e = chunk0 + i;
        if (e < E) {
            int s = ei[e], d = ei[E + e];
            int b = d >> BK_BITS;
            int p = atomicAdd(&resv[b], 1);
            binned[p] = (unsigned)s | ((unsigned)(d & (BK_SIZE - 1)) << 20);
        }
    }
}

__global__ __launch_bounds__(256) void b4_build(
    const unsigned* __restrict__ binned, const int* __restrict__ cursor,
    int2* __restrict__ row2, int* __restrict__ csr, int n)
{
    __shared__ int deg[BK_SIZE];
    __shared__ int off[BK_SIZE];
    __shared__ int ts[256];
    int tid = threadIdx.x;
    int b = blockIdx.x;
    int node0 = b << BK_BITS;
    int nn = min(BK_SIZE, n - node0);
    int e0 = b * BK_CAP;
    int e1 = cursor[b];

    for (int i = tid; i < BK_SIZE; i += 256) deg[i] = 0;
    __syncthreads();
    for (int j = e0 + tid; j < e1; j += 256)
        atomicAdd(&deg[binned[j] >> 20], 1);
    __syncthreads();

    int base4 = tid * 4;
    int v0 = deg[base4], v1 = deg[base4 + 1], v2 = deg[base4 + 2], v3 = deg[base4 + 3];
    int ssum = v0 + v1 + v2 + v3;
    ts[tid] = ssum;
    __syncthreads();
    for (int o = 1; o < 256; o <<= 1) {
        int xv = (tid >= o) ? ts[tid - o] : 0;
        __syncthreads();
        ts[tid] += xv;
        __syncthreads();
    }
    int run = ts[tid] - ssum;
    off[base4 + 0] = run;
    if (base4 + 0 < nn) row2[node0 + base4 + 0] = make_int2(e0 + run, e0 + run + v0);
    run += v0;
    off[base4 + 1] = run;
    if (base4 + 1 < nn) row2[node0 + base4 + 1] = make_int2(e0 + run, e0 + run + v1);
    run += v1;
    off[base4 + 2] = run;
    if (base4 + 2 < nn) row2[node0 + base4 + 2] = make_int2(e0 + run, e0 + run + v2);
    run += v2;
    off[base4 + 3] = run;
    if (base4 + 3 < nn) row2[node0 + base4 + 3] = make_int2(e0 + run, e0 + run + v3);
    __syncthreads();

    for (int i = tid; i < BK_SIZE; i += 256) deg[i] = off[i];
    __syncthreads();
    for (int j = e0 + tid; j < e1; j += 256) {
        unsigned pk = binned[j];
        int dl = pk >> 20;
        int s = (int)(pk & 0xFFFFFu);
        int p = atomicAdd(&deg[dl], 1);
        csr[e0 + p] = s;
    }
}

// ---- fused softmax + aggregation: 4 edges/batch via lane groups ----
// Lane l: g=l>>4 owns edge j0+g; q=l&15 owns cols q*8..q*8+7 (head q>>1).
// Per 4 edges: 1 csr dword + 1 asrc dword + 1 h dwordx4 per lane (vs 8 VMEM
// before), exp once per (edge,head) group. Tail lanes get w=0 (branch-free).
// Epilogue: shfl_xor(16,32) cross-group reduce; lanes 0-15 store 32 B each.
__global__ __launch_bounds__(256) void agg_kernel(
    const int* __restrict__ csr, const int2* __restrict__ row2,
    const float* __restrict__ asrc, const float* __restrict__ adst,
    const __hip_bfloat16* __restrict__ hb, const float* __restrict__ bias,
    float* __restrict__ out, int n)
{
    int wave = threadIdx.x >> 6;
    int lane = threadIdx.x & 63;
    int d = blockIdx.x * 4 + wave;
    if (d >= n) return;

    int g = lane >> 4;      // edge slot within batch
    int q = lane & 15;      // col quad: cols q*8..q*8+7
    int h = q >> 1;         // head for these cols

    int2 se = row2[d];
    int start = se.x, end = se.y;

    float adl = adst[d * HEADS + h];
    const uint4* h4 = (const uint4*)hb;     // row = 16 uint4

    // self loop as a batch with w!=0 only in group 0
    float wsum, acc[8];
    {
        float a = asrc[d * HEADS + h] + adl;
        float w0 = (g == 0) ? __expf(lrelu(a)) : 0.f;
        uint4 uv = h4[(unsigned)d * 16 + q];
        acc[0] = w0 * bflo(uv.x); acc[1] = w0 * bfhi(uv.x);
        acc[2] = w0 * bflo(uv.y); acc[3] = w0 * bfhi(uv.y);
        acc[4] = w0 * bflo(uv.z); acc[5] = w0 * bfhi(uv.z);
        acc[6] = w0 * bflo(uv.w); acc[7] = w0 * bfhi(uv.w);
        wsum = w0;
    }

    for (int j0 = start; j0 < end; j0 += 4) {
        int idx = j0 + g;
        int sg = csr[min(idx, end - 1)];
        float a = asrc[sg * HEADS + h] + adl;
        float w = (idx < end) ? __expf(lrelu(a)) : 0.f;
        uint4 uv = h4[(unsigned)sg * 16 + q];
        acc[0] = fmaf(w, bflo(uv.x), acc[0]);
        acc[1] = fmaf(w, bfhi(uv.x), acc[1]);
        acc[2] = fmaf(w, bflo(uv.y), acc[2]);
        acc[3] = fmaf(w, bfhi(uv.y), acc[3]);
        acc[4] = fmaf(w, bflo(uv.z), acc[4]);
        acc[5] = fmaf(w, bfhi(uv.z), acc[5]);
        acc[6] = fmaf(w, bflo(uv.w), acc[6]);
        acc[7] = fmaf(w, bfhi(uv.w), acc[7]);
        wsum += w;
    }

    // cross-group reduce (groups are lanes {0-15}{16-31}{32-47}{48-63})
    #pragma unroll
    for (int r = 0; r < 8; ++r) {
        acc[r] += __shfl_xor(acc[r], 16, 64);
        acc[r] += __shfl_xor(acc[r], 32, 64);
    }
    wsum += __shfl_xor(wsum, 16, 64);
    wsum += __shfl_xor(wsum, 32, 64);

    if (g == 0) {
        float inv = 1.f / (wsum + 1e-16f);
        const float4* bias4 = (const float4*)bias;
        float4 b0 = bias4[q * 2], b1 = bias4[q * 2 + 1];
        float4 o0, o1;
        o0.x = fmaxf(fmaf(acc[0], inv, b0.x), 0.f);
        o0.y = fmaxf(fmaf(acc[1], inv, b0.y), 0.f);
        o0.z = fmaxf(fmaf(acc[2], inv, b0.z), 0.f);
        o0.w = fmaxf(fmaf(acc[3], inv, b0.w), 0.f);
        o1.x = fmaxf(fmaf(acc[4], inv, b1.x), 0.f);
        o1.y = fmaxf(fmaf(acc[5], inv, b1.y), 0.f);
        o1.z = fmaxf(fmaf(acc[6], inv, b1.z), 0.f);
        o1.w = fmaxf(fmaf(acc[7], inv, b1.w), 0.f);
        float4* op = (float4*)(out + (size_t)d * HC + q * 8);
        op[0] = o0; op[1] = o1;
    }
}

extern "C" void kernel_launch(void* const* d_in, const int* in_sizes, int n_in,
                              void* d_out, int out_size, void* d_ws, size_t ws_size,
                              hipStream_t stream) {
    const float* x       = (const float*)d_in[0];
    const float* W       = (const float*)d_in[1];
    const float* att_src = (const float*)d_in[2];
    const float* att_dst = (const float*)d_in[3];
    const float* bias    = (const float*)d_in[4];
    const int*   ei      = (const int*)d_in[5];

    int n = in_sizes[0] / IN_CH;        // 100000
    int E = in_sizes[5] / 2;            // 1600000
    float* out = (float*)d_out;
    int nbuck = (n + BK_SIZE - 1) >> BK_BITS;   // 98 (<=256 required)

    // workspace layout
    char* ws = (char*)d_ws;
    __hip_bfloat16* hb = (__hip_bfloat16*)ws; ws += (size_t)n * HC * 2;  // 25.6 MB
    float* asrc = (float*)ws;   ws += (size_t)n * HEADS * 4;             // 3.2 MB
    float* adst = (float*)ws;   ws += (size_t)n * HEADS * 4;             // 3.2 MB
    int*   csr  = (int*)ws;     ws += ((size_t)nbuck * BK_CAP + 64) * 4; // 7.2 MB
    unsigned* binned = (unsigned*)ws; ws += (size_t)nbuck * BK_CAP * 4;  // 7.2 MB
    int2*  row2 = (int2*)ws;    ws += (size_t)n * 8;                     // 0.8 MB
    int*   cursor=(int*)ws;     ws += 256 * 4;
    float* wa   = (float*)ws;   ws += IN_CH * 16 * 4;                    // 4 KB

    init_kernel<<<1, 256, 0, stream>>>(W, att_src, att_dst, wa, cursor, nbuck);

    int pblk = (n + 63) / 64;   // 1563
    proj_kernel<<<pblk, 256, 0, stream>>>(x, W, wa, hb, asrc, adst, n);

    int binblk = (E + BIN_CHUNK - 1) / BIN_CHUNK;
    b3_bin<<<binblk, 256, 0, stream>>>(ei, E, nbuck, cursor, binned);
    b4_build<<<nbuck, 256, 0, stream>>>(binned, cursor, row2, csr, n);

    int ablk = (n + 3) / 4;
    agg_kernel<<<ablk, 256, 0, stream>>>(csr, row2, asrc, adst, hb, bias, out, n);
}

// Round 14
// 174.129 us; speedup vs baseline: 1.0670x; 1.0670x over previous
//
#include <hip/hip_runtime.h>
#include <hip/hip_bf16.h>

#define IN_CH 64
#define HC 128          // HEADS * OUT_CH
#define HEADS 8
#define OUT_CH 16
#define NEG 0.2f

#define BK_BITS 10
#define BK_SIZE 1024    // nodes per bucket
#define BK_CAP 18432    // padded capacity per bucket (mean 16384, 16-sigma margin)
#define BIN_CHUNK 4096  // edges per b3 block

typedef __attribute__((ext_vector_type(8))) short short8;
typedef __attribute__((ext_vector_type(4))) float f32x4;

__device__ __forceinline__ float lrelu(float x) {
    return fmaxf(x, NEG * x);   // valid for NEG<1
}
__device__ __forceinline__ short f2bf(float f) {
    __hip_bfloat16 b = __float2bfloat16(f);
    return *(short*)&b;
}

// ---- init: bucket cursors + fused attention weights ----
__global__ void init_kernel(const float* __restrict__ W,
                            const float* __restrict__ att_src,
                            const float* __restrict__ att_dst,
                            float* __restrict__ wa,
                            int* __restrict__ cursor, int nbuck)
{
    int t = threadIdx.x;
    if (t < nbuck) cursor[t] = t * BK_CAP;
    for (int idx = t; idx < IN_CH * 16; idx += 256) {
        int k = idx >> 4, i = idx & 15;
        const float* av = (i < 8) ? att_src : att_dst;
        int hd = (i < 8) ? i : i - 8;
        float s = 0.f;
        #pragma unroll
        for (int c = 0; c < 16; ++c)
            s += W[k * HC + hd * 16 + c] * av[hd * 16 + c];
        wa[idx] = s;
    }
}

// ---- projection via MFMA: h = bf16(x) @ bf16(W), logits fused as tile 8 ----
__global__ __launch_bounds__(256) void proj_kernel(
    const float* __restrict__ x, const float* __restrict__ W,
    const float* __restrict__ wa,
    __hip_bfloat16* __restrict__ hb, float* __restrict__ asrc,
    float* __restrict__ adst, int n)
{
    int lane = threadIdx.x & 63;
    int w    = threadIdx.x >> 6;
    int m    = lane & 15;     // A-row / B-col / D-col
    int kg   = lane >> 4;     // k-group

    int rowbase = blockIdx.x * 64 + w * 16;

    short8 bf[9][2];
    #pragma unroll
    for (int s = 0; s < 2; ++s) {
        #pragma unroll
        for (int t = 0; t < 8; ++t) {
            #pragma unroll
            for (int j = 0; j < 8; ++j) {
                int k = s * 32 + kg * 8 + j;
                bf[t][s][j] = f2bf(W[k * HC + t * 16 + m]);
            }
        }
        #pragma unroll
        for (int j = 0; j < 8; ++j) {
            int k = s * 32 + kg * 8 + j;
            bf[8][s][j] = f2bf(wa[k * 16 + m]);
        }
    }

    int rowc = min(rowbase + m, n - 1);
    const float* xp = x + (long long)rowc * IN_CH + kg * 8;
    short8 af[2];
    #pragma unroll
    for (int s = 0; s < 2; ++s) {
        float4 f0 = *(const float4*)(xp + s * 32);
        float4 f1 = *(const float4*)(xp + s * 32 + 4);
        af[s][0] = f2bf(f0.x); af[s][1] = f2bf(f0.y);
        af[s][2] = f2bf(f0.z); af[s][3] = f2bf(f0.w);
        af[s][4] = f2bf(f1.x); af[s][5] = f2bf(f1.y);
        af[s][6] = f2bf(f1.z); af[s][7] = f2bf(f1.w);
    }

    f32x4 acc[9];
    #pragma unroll
    for (int t = 0; t < 9; ++t) acc[t] = (f32x4){0.f, 0.f, 0.f, 0.f};

    #pragma unroll
    for (int s = 0; s < 2; ++s)
        #pragma unroll
        for (int t = 0; t < 9; ++t)
            acc[t] = __builtin_amdgcn_mfma_f32_16x16x32_bf16(
                         af[s], bf[t][s], acc[t], 0, 0, 0);

    #pragma unroll
    for (int r = 0; r < 4; ++r) {
        int orow = rowbase + kg * 4 + r;
        if (orow < n) {
            __hip_bfloat16* hp = hb + (long long)orow * HC + m;
            #pragma unroll
            for (int t = 0; t < 8; ++t)
                hp[t * 16] = __float2bfloat16(acc[t][r]);
            float av = acc[8][r];
            if (m < 8) asrc[orow * HEADS + m] = av;
            else       adst[orow * HEADS + (m - 8)] = av;
        }
    }
}

// ---- bucketed CSR build (fixed-capacity padded buckets) ----
__global__ __launch_bounds__(256) void b3_bin(
    const int* __restrict__ ei, int E, int nbuck,
    int* __restrict__ cursor, unsigned* __restrict__ binned)
{
    __shared__ int cnt[256];
    __shared__ int resv[256];
    int tid = threadIdx.x;
    int chunk0 = blockIdx.x * BIN_CHUNK;
    cnt[tid] = 0;
    __syncthreads();
    for (int i = tid; i < BIN_CHUNK; i += 256) {
        int e = chunk0 + i;
        if (e < E) atomicAdd(&cnt[ei[E + e] >> BK_BITS], 1);
    }
    __syncthreads();
    if (tid < nbuck) resv[tid] = cnt[tid] ? atomicAdd(&cursor[tid], cnt[tid]) : 0;
    __syncthreads();
    for (int i = tid; i < BIN_CHUNK; i += 256) {
        int e = chunk0 + i;
        if (e < E) {
            int s = ei[e], d = ei[E + e];
            int b = d >> BK_BITS;
            int p = atomicAdd(&resv[b], 1);
            binned[p] = (unsigned)s | ((unsigned)(d & (BK_SIZE - 1)) << 20);
        }
    }
}

__global__ __launch_bounds__(256) void b4_build(
    const unsigned* __restrict__ binned, const int* __restrict__ cursor,
    int2* __restrict__ row2, int* __restrict__ csr, int n)
{
    __shared__ int deg[BK_SIZE];
    __shared__ int off[BK_SIZE];
    __shared__ int ts[256];
    int tid = threadIdx.x;
    int b = blockIdx.x;
    int node0 = b << BK_BITS;
    int nn = min(BK_SIZE, n - node0);
    int e0 = b * BK_CAP;
    int e1 = cursor[b];

    for (int i = tid; i < BK_SIZE; i += 256) deg[i] = 0;
    __syncthreads();
    for (int j = e0 + tid; j < e1; j += 256)
        atomicAdd(&deg[binned[j] >> 20], 1);
    __syncthreads();

    int base4 = tid * 4;
    int v0 = deg[base4], v1 = deg[base4 + 1], v2 = deg[base4 + 2], v3 = deg[base4 + 3];
    int ssum = v0 + v1 + v2 + v3;
    ts[tid] = ssum;
    __syncthreads();
    for (int o = 1; o < 256; o <<= 1) {
        int xv = (tid >= o) ? ts[tid - o] : 0;
        __syncthreads();
        ts[tid] += xv;
        __syncthreads();
    }
    int run = ts[tid] - ssum;
    off[base4 + 0] = run;
    if (base4 + 0 < nn) row2[node0 + base4 + 0] = make_int2(e0 + run, e0 + run + v0);
    run += v0;
    off[base4 + 1] = run;
    if (base4 + 1 < nn) row2[node0 + base4 + 1] = make_int2(e0 + run, e0 + run + v1);
    run += v1;
    off[base4 + 2] = run;
    if (base4 + 2 < nn) row2[node0 + base4 + 2] = make_int2(e0 + run, e0 + run + v2);
    run += v2;
    off[base4 + 3] = run;
    if (base4 + 3 < nn) row2[node0 + base4 + 3] = make_int2(e0 + run, e0 + run + v3);
    __syncthreads();

    for (int i = tid; i < BK_SIZE; i += 256) deg[i] = off[i];
    __syncthreads();
    for (int j = e0 + tid; j < e1; j += 256) {
        unsigned pk = binned[j];
        int dl = pk >> 20;
        int s = (int)(pk & 0xFFFFFu);
        int p = atomicAdd(&deg[dl], 1);
        csr[e0 + p] = s;
    }
}

// ---- fused softmax + aggregation: own-head exp, unroll-8 for MLP ----
// Round-12 form (92.6us) had 12 loads in flight; round-13's lane-group cut
// VMEM count but killed MLP (100us, VALUBusy 39%). This is round-12 with an
// 8-edge main loop: ~24 independent loads in flight per wave.
__global__ __launch_bounds__(256) void agg_kernel(
    const int* __restrict__ csr, const int2* __restrict__ row2,
    const float* __restrict__ asrc, const float* __restrict__ adst,
    const __hip_bfloat16* __restrict__ hb, const float* __restrict__ bias,
    float* __restrict__ out, int n)
{
    int wave = threadIdx.x >> 6;
    int lane = threadIdx.x & 63;
    int d = blockIdx.x * 4 + wave;
    if (d >= n) return;

    int hO = lane >> 3;         // head owning this lane's output cols

    int2 se = row2[d];
    int start = se.x, end = se.y;

    float adstv = adst[d * HEADS + hO];
    const unsigned* hu = (const unsigned*)hb;

    // self loop
    float w = __expf(lrelu(asrc[d * HEADS + hO] + adstv));
    unsigned u = hu[(long long)d * 64 + lane];
    float denom = w;
    float accx = w * __uint_as_float(u << 16);
    float accy = w * __uint_as_float(u & 0xFFFF0000u);

    int j = start;
    for (; j + 7 < end; j += 8) {
        int s0 = csr[j],     s1 = csr[j + 1], s2 = csr[j + 2], s3 = csr[j + 3];
        int s4 = csr[j + 4], s5 = csr[j + 5], s6 = csr[j + 6], s7 = csr[j + 7];
        float w0 = __expf(lrelu(asrc[s0 * HEADS + hO] + adstv));
        float w1 = __expf(lrelu(asrc[s1 * HEADS + hO] + adstv));
        float w2 = __expf(lrelu(asrc[s2 * HEADS + hO] + adstv));
        float w3 = __expf(lrelu(asrc[s3 * HEADS + hO] + adstv));
        float w4 = __expf(lrelu(asrc[s4 * HEADS + hO] + adstv));
        float w5 = __expf(lrelu(asrc[s5 * HEADS + hO] + adstv));
        float w6 = __expf(lrelu(asrc[s6 * HEADS + hO] + adstv));
        float w7 = __expf(lrelu(asrc[s7 * HEADS + hO] + adstv));
        unsigned u0 = hu[(long long)s0 * 64 + lane];
        unsigned u1 = hu[(long long)s1 * 64 + lane];
        unsigned u2 = hu[(long long)s2 * 64 + lane];
        unsigned u3 = hu[(long long)s3 * 64 + lane];
        unsigned u4 = hu[(long long)s4 * 64 + lane];
        unsigned u5 = hu[(long long)s5 * 64 + lane];
        unsigned u6 = hu[(long long)s6 * 64 + lane];
        unsigned u7 = hu[(long long)s7 * 64 + lane];
        denom += ((w0 + w1) + (w2 + w3)) + ((w4 + w5) + (w6 + w7));
        accx = fmaf(w0, __uint_as_float(u0 << 16), accx);
        accy = fmaf(w0, __uint_as_float(u0 & 0xFFFF0000u), accy);
        accx = fmaf(w1, __uint_as_float(u1 << 16), accx);
        accy = fmaf(w1, __uint_as_float(u1 & 0xFFFF0000u), accy);
        accx = fmaf(w2, __uint_as_float(u2 << 16), accx);
        accy = fmaf(w2, __uint_as_float(u2 & 0xFFFF0000u), accy);
        accx = fmaf(w3, __uint_as_float(u3 << 16), accx);
        accy = fmaf(w3, __uint_as_float(u3 & 0xFFFF0000u), accy);
        accx = fmaf(w4, __uint_as_float(u4 << 16), accx);
        accy = fmaf(w4, __uint_as_float(u4 & 0xFFFF0000u), accy);
        accx = fmaf(w5, __uint_as_float(u5 << 16), accx);
        accy = fmaf(w5, __uint_as_float(u5 & 0xFFFF0000u), accy);
        accx = fmaf(w6, __uint_as_float(u6 << 16), accx);
        accy = fmaf(w6, __uint_as_float(u6 & 0xFFFF0000u), accy);
        accx = fmaf(w7, __uint_as_float(u7 << 16), accx);
        accy = fmaf(w7, __uint_as_float(u7 & 0xFFFF0000u), accy);
    }
    for (; j + 3 < end; j += 4) {
        int s0 = csr[j], s1 = csr[j + 1], s2 = csr[j + 2], s3 = csr[j + 3];
        float w0 = __expf(lrelu(asrc[s0 * HEADS + hO] + adstv));
        float w1 = __expf(lrelu(asrc[s1 * HEADS + hO] + adstv));
        float w2 = __expf(lrelu(asrc[s2 * HEADS + hO] + adstv));
        float w3 = __expf(lrelu(asrc[s3 * HEADS + hO] + adstv));
        unsigned u0 = hu[(long long)s0 * 64 + lane];
        unsigned u1 = hu[(long long)s1 * 64 + lane];
        unsigned u2 = hu[(long long)s2 * 64 + lane];
        unsigned u3 = hu[(long long)s3 * 64 + lane];
        denom += (w0 + w1) + (w2 + w3);
        accx = fmaf(w0, __uint_as_float(u0 << 16), accx);
        accy = fmaf(w0, __uint_as_float(u0 & 0xFFFF0000u), accy);
        accx = fmaf(w1, __uint_as_float(u1 << 16), accx);
        accy = fmaf(w1, __uint_as_float(u1 & 0xFFFF0000u), accy);
        accx = fmaf(w2, __uint_as_float(u2 << 16), accx);
        accy = fmaf(w2, __uint_as_float(u2 & 0xFFFF0000u), accy);
        accx = fmaf(w3, __uint_as_float(u3 << 16), accx);
        accy = fmaf(w3, __uint_as_float(u3 & 0xFFFF0000u), accy);
    }
    for (; j < end; ++j) {
        int s0 = csr[j];
        float w0 = __expf(lrelu(asrc[s0 * HEADS + hO] + adstv));
        unsigned u0 = hu[(long long)s0 * 64 + lane];
        denom += w0;
        accx = fmaf(w0, __uint_as_float(u0 << 16), accx);
        accy = fmaf(w0, __uint_as_float(u0 & 0xFFFF0000u), accy);
    }

    float inv = 1.f / (denom + 1e-16f);
    const float2* b2 = (const float2*)bias;
    float2 bb = b2[lane];
    float2 o;
    o.x = fmaxf(fmaf(accx, inv, bb.x), 0.f);
    o.y = fmaxf(fmaf(accy, inv, bb.y), 0.f);
    ((float2*)out)[(long long)d * 64 + lane] = o;
}

extern "C" void kernel_launch(void* const* d_in, const int* in_sizes, int n_in,
                              void* d_out, int out_size, void* d_ws, size_t ws_size,
                              hipStream_t stream) {
    const float* x       = (const float*)d_in[0];
    const float* W       = (const float*)d_in[1];
    const float* att_src = (const float*)d_in[2];
    const float* att_dst = (const float*)d_in[3];
    const float* bias    = (const float*)d_in[4];
    const int*   ei      = (const int*)d_in[5];

    int n = in_sizes[0] / IN_CH;        // 100000
    int E = in_sizes[5] / 2;            // 1600000
    float* out = (float*)d_out;
    int nbuck = (n + BK_SIZE - 1) >> BK_BITS;   // 98 (<=256 required)

    // workspace layout
    char* ws = (char*)d_ws;
    __hip_bfloat16* hb = (__hip_bfloat16*)ws; ws += (size_t)n * HC * 2;  // 25.6 MB
    float* asrc = (float*)ws;   ws += (size_t)n * HEADS * 4;             // 3.2 MB
    float* adst = (float*)ws;   ws += (size_t)n * HEADS * 4;             // 3.2 MB
    int*   csr  = (int*)ws;     ws += ((size_t)nbuck * BK_CAP + 64) * 4; // 7.2 MB
    unsigned* binned = (unsigned*)ws; ws += (size_t)nbuck * BK_CAP * 4;  // 7.2 MB
    int2*  row2 = (int2*)ws;    ws += (size_t)n * 8;                     // 0.8 MB
    int*   cursor=(int*)ws;     ws += 256 * 4;
    float* wa   = (float*)ws;   ws += IN_CH * 16 * 4;                    // 4 KB

    init_kernel<<<1, 256, 0, stream>>>(W, att_src, att_dst, wa, cursor, nbuck);

    int pblk = (n + 63) / 64;   // 1563
    proj_kernel<<<pblk, 256, 0, stream>>>(x, W, wa, hb, asrc, adst, n);

    int binblk = (E + BIN_CHUNK - 1) / BIN_CHUNK;
    b3_bin<<<binblk, 256, 0, stream>>>(ei, E, nbuck, cursor, binned);
    b4_build<<<nbuck, 256, 0, stream>>>(binned, cursor, row2, csr, n);

    int ablk = (n + 3) / 4;
    agg_kernel<<<ablk, 256, 0, stream>>>(csr, row2, asrc, adst, hb, bias, out, n);
}

// Round 15
// 168.641 us; speedup vs baseline: 1.1017x; 1.0325x over previous
//
#include <hip/hip_runtime.h>
#include <hip/hip_bf16.h>

#define IN_CH 64
#define HC 128          // HEADS * OUT_CH
#define HEADS 8
#define OUT_CH 16
#define NEG 0.2f

#define BK_BITS 10
#define BK_SIZE 1024    // nodes per bucket
#define BK_CAP 18432    // padded capacity per bucket (mean 16384, 16-sigma margin)
#define BIN_CHUNK 4096  // edges per bin block

typedef __attribute__((ext_vector_type(8))) short short8;
typedef __attribute__((ext_vector_type(4))) float f32x4;

__device__ __forceinline__ float lrelu(float x) {
    return fmaxf(x, NEG * x);   // valid for NEG<1
}
__device__ __forceinline__ short f2bf(float f) {
    __hip_bfloat16 b = __float2bfloat16(f);
    return *(short*)&b;
}

// ---- fused kernel: blocks [0,nbin) do edge binning; rest do MFMA proj ----
// proj and binning are independent (proj: x,W -> hb/logits; bin: ei -> binned)
// and use complementary pipes (MFMA/VMEM vs LDS-atomic). Fusing overlaps them
// and removes a launch gap. Bin blocks first: b4's critical path starts early.
// cursor holds COUNTS only (memset 0 upfront); slot = bucket*BK_CAP + count.
// wa (fused att weights: a_src=(x@W)@att == x@wa) recomputed per proj block
// in LDS -- 25M redundant FMA grid-wide, free vs a dedicated init kernel.
__global__ __launch_bounds__(256) void fused_proj_bin(
    const float* __restrict__ x, const float* __restrict__ W,
    const float* __restrict__ att_src, const float* __restrict__ att_dst,
    __hip_bfloat16* __restrict__ hb, float* __restrict__ asrc,
    float* __restrict__ adst, int n,
    const int* __restrict__ ei, int E, int nbuck,
    int* __restrict__ cursor, unsigned* __restrict__ binned, int nbin)
{
    __shared__ float sh[1024];   // bin: cnt[256]+resv[256]; proj: wa[64][16]
    int tid = threadIdx.x;

    if ((int)blockIdx.x < nbin) {
        // ---- bin body (b3) ----
        int* cnt  = (int*)sh;
        int* resv = (int*)sh + 256;
        int chunk0 = blockIdx.x * BIN_CHUNK;
        cnt[tid] = 0;
        __syncthreads();
        for (int i = tid; i < BIN_CHUNK; i += 256) {
            int e = chunk0 + i;
            if (e < E) atomicAdd(&cnt[ei[E + e] >> BK_BITS], 1);
        }
        __syncthreads();
        if (tid < nbuck)
            resv[tid] = cnt[tid] ? (tid * BK_CAP + atomicAdd(&cursor[tid], cnt[tid])) : 0;
        __syncthreads();
        for (int i = tid; i < BIN_CHUNK; i += 256) {
            int e = chunk0 + i;
            if (e < E) {
                int s = ei[e], d = ei[E + e];
                int b = d >> BK_BITS;
                int p = atomicAdd(&resv[b], 1);
                binned[p] = (unsigned)s | ((unsigned)(d & (BK_SIZE - 1)) << 20);
            }
        }
        return;
    }

    // ---- proj body ----
    // wa[k][i]: i<8 -> src head i, i>=8 -> dst head i-8
    for (int idx = tid; idx < IN_CH * 16; idx += 256) {
        int k = idx >> 4, i = idx & 15;
        const float* av = (i < 8) ? att_src : att_dst;
        int hd = (i < 8) ? i : i - 8;
        float s = 0.f;
        #pragma unroll
        for (int c = 0; c < 16; ++c)
            s += W[k * HC + hd * 16 + c] * av[hd * 16 + c];
        sh[idx] = s;
    }
    __syncthreads();

    int lane = threadIdx.x & 63;
    int w    = threadIdx.x >> 6;
    int m    = lane & 15;     // A-row / B-col / D-col
    int kg   = lane >> 4;     // k-group

    int rowbase = ((int)blockIdx.x - nbin) * 64 + w * 16;

    short8 bf[9][2];
    #pragma unroll
    for (int s = 0; s < 2; ++s) {
        #pragma unroll
        for (int t = 0; t < 8; ++t) {
            #pragma unroll
            for (int j = 0; j < 8; ++j) {
                int k = s * 32 + kg * 8 + j;
                bf[t][s][j] = f2bf(W[k * HC + t * 16 + m]);
            }
        }
        #pragma unroll
        for (int j = 0; j < 8; ++j) {
            int k = s * 32 + kg * 8 + j;
            bf[8][s][j] = f2bf(sh[k * 16 + m]);
        }
    }

    int rowc = min(rowbase + m, n - 1);
    const float* xp = x + (long long)rowc * IN_CH + kg * 8;
    short8 af[2];
    #pragma unroll
    for (int s = 0; s < 2; ++s) {
        float4 f0 = *(const float4*)(xp + s * 32);
        float4 f1 = *(const float4*)(xp + s * 32 + 4);
        af[s][0] = f2bf(f0.x); af[s][1] = f2bf(f0.y);
        af[s][2] = f2bf(f0.z); af[s][3] = f2bf(f0.w);
        af[s][4] = f2bf(f1.x); af[s][5] = f2bf(f1.y);
        af[s][6] = f2bf(f1.z); af[s][7] = f2bf(f1.w);
    }

    f32x4 acc[9];
    #pragma unroll
    for (int t = 0; t < 9; ++t) acc[t] = (f32x4){0.f, 0.f, 0.f, 0.f};

    #pragma unroll
    for (int s = 0; s < 2; ++s)
        #pragma unroll
        for (int t = 0; t < 9; ++t)
            acc[t] = __builtin_amdgcn_mfma_f32_16x16x32_bf16(
                         af[s], bf[t][s], acc[t], 0, 0, 0);

    #pragma unroll
    for (int r = 0; r < 4; ++r) {
        int orow = rowbase + kg * 4 + r;
        if (orow < n) {
            __hip_bfloat16* hp = hb + (long long)orow * HC + m;
            #pragma unroll
            for (int t = 0; t < 8; ++t)
                hp[t * 16] = __float2bfloat16(acc[t][r]);
            float av = acc[8][r];
            if (m < 8) asrc[orow * HEADS + m] = av;
            else       adst[orow * HEADS + (m - 8)] = av;
        }
    }
}

// ---- b4: per-bucket degree count + scan -> row2, scatter csr ----
__global__ __launch_bounds__(256) void b4_build(
    const unsigned* __restrict__ binned, const int* __restrict__ cursor,
    int2* __restrict__ row2, int* __restrict__ csr, int n)
{
    __shared__ int deg[BK_SIZE];
    __shared__ int off[BK_SIZE];
    __shared__ int ts[256];
    int tid = threadIdx.x;
    int b = blockIdx.x;
    int node0 = b << BK_BITS;
    int nn = min(BK_SIZE, n - node0);
    int e0 = b * BK_CAP;
    int e1 = e0 + cursor[b];    // cursor holds the bucket count

    for (int i = tid; i < BK_SIZE; i += 256) deg[i] = 0;
    __syncthreads();
    for (int j = e0 + tid; j < e1; j += 256)
        atomicAdd(&deg[binned[j] >> 20], 1);
    __syncthreads();

    int base4 = tid * 4;
    int v0 = deg[base4], v1 = deg[base4 + 1], v2 = deg[base4 + 2], v3 = deg[base4 + 3];
    int ssum = v0 + v1 + v2 + v3;
    ts[tid] = ssum;
    __syncthreads();
    for (int o = 1; o < 256; o <<= 1) {
        int xv = (tid >= o) ? ts[tid - o] : 0;
        __syncthreads();
        ts[tid] += xv;
        __syncthreads();
    }
    int run = ts[tid] - ssum;
    off[base4 + 0] = run;
    if (base4 + 0 < nn) row2[node0 + base4 + 0] = make_int2(e0 + run, e0 + run + v0);
    run += v0;
    off[base4 + 1] = run;
    if (base4 + 1 < nn) row2[node0 + base4 + 1] = make_int2(e0 + run, e0 + run + v1);
    run += v1;
    off[base4 + 2] = run;
    if (base4 + 2 < nn) row2[node0 + base4 + 2] = make_int2(e0 + run, e0 + run + v2);
    run += v2;
    off[base4 + 3] = run;
    if (base4 + 3 < nn) row2[node0 + base4 + 3] = make_int2(e0 + run, e0 + run + v3);
    __syncthreads();

    for (int i = tid; i < BK_SIZE; i += 256) deg[i] = off[i];
    __syncthreads();
    for (int j = e0 + tid; j < e1; j += 256) {
        unsigned pk = binned[j];
        int dl = pk >> 20;
        int s = (int)(pk & 0xFFFFFu);
        int p = atomicAdd(&deg[dl], 1);
        csr[e0 + p] = s;
    }
}

// ---- fused softmax + aggregation: own-head exp, unroll-8 (round-14 form,
// 87.3us, at random-gather structural floor -- do not touch) ----
__global__ __launch_bounds__(256) void agg_kernel(
    const int* __restrict__ csr, const int2* __restrict__ row2,
    const float* __restrict__ asrc, const float* __restrict__ adst,
    const __hip_bfloat16* __restrict__ hb, const float* __restrict__ bias,
    float* __restrict__ out, int n)
{
    int wave = threadIdx.x >> 6;
    int lane = threadIdx.x & 63;
    int d = blockIdx.x * 4 + wave;
    if (d >= n) return;

    int hO = lane >> 3;         // head owning this lane's output cols

    int2 se = row2[d];
    int start = se.x, end = se.y;

    float adstv = adst[d * HEADS + hO];
    const unsigned* hu = (const unsigned*)hb;

    // self loop
    float w = __expf(lrelu(asrc[d * HEADS + hO] + adstv));
    unsigned u = hu[(long long)d * 64 + lane];
    float denom = w;
    float accx = w * __uint_as_float(u << 16);
    float accy = w * __uint_as_float(u & 0xFFFF0000u);

    int j = start;
    for (; j + 7 < end; j += 8) {
        int s0 = csr[j],     s1 = csr[j + 1], s2 = csr[j + 2], s3 = csr[j + 3];
        int s4 = csr[j + 4], s5 = csr[j + 5], s6 = csr[j + 6], s7 = csr[j + 7];
        float w0 = __expf(lrelu(asrc[s0 * HEADS + hO] + adstv));
        float w1 = __expf(lrelu(asrc[s1 * HEADS + hO] + adstv));
        float w2 = __expf(lrelu(asrc[s2 * HEADS + hO] + adstv));
        float w3 = __expf(lrelu(asrc[s3 * HEADS + hO] + adstv));
        float w4 = __expf(lrelu(asrc[s4 * HEADS + hO] + adstv));
        float w5 = __expf(lrelu(asrc[s5 * HEADS + hO] + adstv));
        float w6 = __expf(lrelu(asrc[s6 * HEADS + hO] + adstv));
        float w7 = __expf(lrelu(asrc[s7 * HEADS + hO] + adstv));
        unsigned u0 = hu[(long long)s0 * 64 + lane];
        unsigned u1 = hu[(long long)s1 * 64 + lane];
        unsigned u2 = hu[(long long)s2 * 64 + lane];
        unsigned u3 = hu[(long long)s3 * 64 + lane];
        unsigned u4 = hu[(long long)s4 * 64 + lane];
        unsigned u5 = hu[(long long)s5 * 64 + lane];
        unsigned u6 = hu[(long long)s6 * 64 + lane];
        unsigned u7 = hu[(long long)s7 * 64 + lane];
        denom += ((w0 + w1) + (w2 + w3)) + ((w4 + w5) + (w6 + w7));
        accx = fmaf(w0, __uint_as_float(u0 << 16), accx);
        accy = fmaf(w0, __uint_as_float(u0 & 0xFFFF0000u), accy);
        accx = fmaf(w1, __uint_as_float(u1 << 16), accx);
        accy = fmaf(w1, __uint_as_float(u1 & 0xFFFF0000u), accy);
        accx = fmaf(w2, __uint_as_float(u2 << 16), accx);
        accy = fmaf(w2, __uint_as_float(u2 & 0xFFFF0000u), accy);
        accx = fmaf(w3, __uint_as_float(u3 << 16), accx);
        accy = fmaf(w3, __uint_as_float(u3 & 0xFFFF0000u), accy);
        accx = fmaf(w4, __uint_as_float(u4 << 16), accx);
        accy = fmaf(w4, __uint_as_float(u4 & 0xFFFF0000u), accy);
        accx = fmaf(w5, __uint_as_float(u5 << 16), accx);
        accy = fmaf(w5, __uint_as_float(u5 & 0xFFFF0000u), accy);
        accx = fmaf(w6, __uint_as_float(u6 << 16), accx);
        accy = fmaf(w6, __uint_as_float(u6 & 0xFFFF0000u), accy);
        accx = fmaf(w7, __uint_as_float(u7 << 16), accx);
        accy = fmaf(w7, __uint_as_float(u7 & 0xFFFF0000u), accy);
    }
    for (; j + 3 < end; j += 4) {
        int s0 = csr[j], s1 = csr[j + 1], s2 = csr[j + 2], s3 = csr[j + 3];
        float w0 = __expf(lrelu(asrc[s0 * HEADS + hO] + adstv));
        float w1 = __expf(lrelu(asrc[s1 * HEADS + hO] + adstv));
        float w2 = __expf(lrelu(asrc[s2 * HEADS + hO] + adstv));
        float w3 = __expf(lrelu(asrc[s3 * HEADS + hO] + adstv));
        unsigned u0 = hu[(long long)s0 * 64 + lane];
        unsigned u1 = hu[(long long)s1 * 64 + lane];
        unsigned u2 = hu[(long long)s2 * 64 + lane];
        unsigned u3 = hu[(long long)s3 * 64 + lane];
        denom += (w0 + w1) + (w2 + w3);
        accx = fmaf(w0, __uint_as_float(u0 << 16), accx);
        accy = fmaf(w0, __uint_as_float(u0 & 0xFFFF0000u), accy);
        accx = fmaf(w1, __uint_as_float(u1 << 16), accx);
        accy = fmaf(w1, __uint_as_float(u1 & 0xFFFF0000u), accy);
        accx = fmaf(w2, __uint_as_float(u2 << 16), accx);
        accy = fmaf(w2, __uint_as_float(u2 & 0xFFFF0000u), accy);
        accx = fmaf(w3, __uint_as_float(u3 << 16), accx);
        accy = fmaf(w3, __uint_as_float(u3 & 0xFFFF0000u), accy);
    }
    for (; j < end; ++j) {
        int s0 = csr[j];
        float w0 = __expf(lrelu(asrc[s0 * HEADS + hO] + adstv));
        unsigned u0 = hu[(long long)s0 * 64 + lane];
        denom += w0;
        accx = fmaf(w0, __uint_as_float(u0 << 16), accx);
        accy = fmaf(w0, __uint_as_float(u0 & 0xFFFF0000u), accy);
    }

    float inv = 1.f / (denom + 1e-16f);
    const float2* b2 = (const float2*)bias;
    float2 bb = b2[lane];
    float2 o;
    o.x = fmaxf(fmaf(accx, inv, bb.x), 0.f);
    o.y = fmaxf(fmaf(accy, inv, bb.y), 0.f);
    ((float2*)out)[(long long)d * 64 + lane] = o;
}

extern "C" void kernel_launch(void* const* d_in, const int* in_sizes, int n_in,
                              void* d_out, int out_size, void* d_ws, size_t ws_size,
                              hipStream_t stream) {
    const float* x       = (const float*)d_in[0];
    const float* W       = (const float*)d_in[1];
    const float* att_src = (const float*)d_in[2];
    const float* att_dst = (const float*)d_in[3];
    const float* bias    = (const float*)d_in[4];
    const int*   ei      = (const int*)d_in[5];

    int n = in_sizes[0] / IN_CH;        // 100000
    int E = in_sizes[5] / 2;            // 1600000
    float* out = (float*)d_out;
    int nbuck = (n + BK_SIZE - 1) >> BK_BITS;   // 98 (<=256 required)

    // workspace layout
    char* ws = (char*)d_ws;
    __hip_bfloat16* hb = (__hip_bfloat16*)ws; ws += (size_t)n * HC * 2;  // 25.6 MB
    float* asrc = (float*)ws;   ws += (size_t)n * HEADS * 4;             // 3.2 MB
    float* adst = (float*)ws;   ws += (size_t)n * HEADS * 4;             // 3.2 MB
    int*   csr  = (int*)ws;     ws += ((size_t)nbuck * BK_CAP + 64) * 4; // 7.2 MB
    unsigned* binned = (unsigned*)ws; ws += (size_t)nbuck * BK_CAP * 4;  // 7.2 MB
    int2*  row2 = (int2*)ws;    ws += (size_t)n * 8;                     // 0.8 MB
    int*   cursor=(int*)ws;     ws += 256 * 4;

    hipMemsetAsync(cursor, 0, 256 * 4, stream);

    int nbin = (E + BIN_CHUNK - 1) / BIN_CHUNK;     // 391
    int pblk = (n + 63) / 64;                       // 1563
    fused_proj_bin<<<nbin + pblk, 256, 0, stream>>>(
        x, W, att_src, att_dst, hb, asrc, adst, n,
        ei, E, nbuck, cursor, binned, nbin);

    b4_build<<<nbuck, 256, 0, stream>>>(binned, cursor, row2, csr, n);

    int ablk = (n + 3) / 4;
    agg_kernel<<<ablk, 256, 0, stream>>>(csr, row2, asrc, adst, hb, bias, out, n);
}

// Round 16
// 148.386 us; speedup vs baseline: 1.2521x; 1.1365x over previous
//
#include <hip/hip_runtime.h>
#include <hip/hip_bf16.h>

#define IN_CH 64
#define HC 128          // HEADS * OUT_CH
#define HEADS 8
#define OUT_CH 16
#define NEG 0.2f

#define BK_BITS 8
#define BK_SIZE 256     // nodes per bucket
#define BK_CAP 5120     // padded capacity (mean 4092, 16-sigma margin)
#define BIN_CHUNK 4096  // edges per bin block

typedef __attribute__((ext_vector_type(8))) short short8;
typedef __attribute__((ext_vector_type(4))) float f32x4;

__device__ __forceinline__ float lrelu(float x) {
    return fmaxf(x, NEG * x);   // valid for NEG<1
}
__device__ __forceinline__ short f2bf(float f) {
    __hip_bfloat16 b = __float2bfloat16(f);
    return *(short*)&b;
}

// ---- bin: edges -> padded bucket regions, packed src|(dlow<<17) ----
// (src < 2^17; dlow = d & 255 in bits 17..24)
__global__ __launch_bounds__(256) void bin_kernel(
    const int* __restrict__ ei, int E, int nbuck,
    int* __restrict__ cursor, unsigned* __restrict__ binned)
{
    __shared__ int cnt[512];
    __shared__ int resv[512];
    int tid = threadIdx.x;
    int chunk0 = blockIdx.x * BIN_CHUNK;
    for (int i = tid; i < nbuck; i += 256) cnt[i] = 0;
    __syncthreads();
    for (int i = tid; i < BIN_CHUNK; i += 256) {
        int e = chunk0 + i;
        if (e < E) atomicAdd(&cnt[ei[E + e] >> BK_BITS], 1);
    }
    __syncthreads();
    for (int i = tid; i < nbuck; i += 256)
        if (cnt[i]) resv[i] = i * BK_CAP + atomicAdd(&cursor[i], cnt[i]);
    __syncthreads();
    for (int i = tid; i < BIN_CHUNK; i += 256) {
        int e = chunk0 + i;
        if (e < E) {
            int s = ei[e], d = ei[E + e];
            int b = d >> BK_BITS;
            int p = atomicAdd(&resv[b], 1);
            binned[p] = (unsigned)s | ((unsigned)(d & (BK_SIZE - 1)) << 17);
        }
    }
}

// ---- fused: blocks [0,nbuck) build CSR for bucket b (dep: bin only);
//      blocks [nbuck,..) do MFMA proj (independent). b4 hides under proj. ----
__global__ __launch_bounds__(256) void fused_proj_b4(
    const float* __restrict__ x, const float* __restrict__ W,
    const float* __restrict__ att_src, const float* __restrict__ att_dst,
    __hip_bfloat16* __restrict__ hb, float* __restrict__ asrc,
    float* __restrict__ adst, int n,
    const unsigned* __restrict__ binned, const int* __restrict__ cursor,
    int2* __restrict__ row2, int* __restrict__ csr, int nbuck)
{
    __shared__ float sh[1024];   // b4: deg[256]+ts[256]; proj: wa[64][16]
    int tid = threadIdx.x;

    if ((int)blockIdx.x < nbuck) {
        // ---- b4 body: 256-node bucket, 256-wide scan ----
        int* deg = (int*)sh;
        int* ts  = (int*)sh + 256;
        int b = blockIdx.x;
        int node0 = b << BK_BITS;
        int nn = min(BK_SIZE, n - node0);
        int e0 = b * BK_CAP;
        int e1 = e0 + cursor[b];        // cursor holds bucket count

        deg[tid] = 0;
        __syncthreads();
        for (int j = e0 + tid; j < e1; j += 256)
            atomicAdd(&deg[binned[j] >> 17], 1);
        __syncthreads();

        int v = deg[tid];
        ts[tid] = v;
        __syncthreads();
        for (int o = 1; o < 256; o <<= 1) {
            int xv = (tid >= o) ? ts[tid - o] : 0;
            __syncthreads();
            ts[tid] += xv;
            __syncthreads();
        }
        int excl = ts[tid] - v;
        if (tid < nn) row2[node0 + tid] = make_int2(e0 + excl, e0 + excl + v);
        __syncthreads();
        deg[tid] = excl;                // per-node scatter cursor
        __syncthreads();
        for (int j = e0 + tid; j < e1; j += 256) {
            unsigned pk = binned[j];
            int dl = pk >> 17;
            int s = (int)(pk & 0x1FFFFu);
            int p = atomicAdd(&deg[dl], 1);
            csr[e0 + p] = s;
        }
        return;
    }

    // ---- proj body (round-15 form, known-good) ----
    for (int idx = tid; idx < IN_CH * 16; idx += 256) {
        int k = idx >> 4, i = idx & 15;
        const float* av = (i < 8) ? att_src : att_dst;
        int hd = (i < 8) ? i : i - 8;
        float s = 0.f;
        #pragma unroll
        for (int c = 0; c < 16; ++c)
            s += W[k * HC + hd * 16 + c] * av[hd * 16 + c];
        sh[idx] = s;
    }
    __syncthreads();

    int lane = threadIdx.x & 63;
    int w    = threadIdx.x >> 6;
    int m    = lane & 15;     // A-row / B-col / D-col
    int kg   = lane >> 4;     // k-group

    int rowbase = ((int)blockIdx.x - nbuck) * 64 + w * 16;

    short8 bf[9][2];
    #pragma unroll
    for (int s = 0; s < 2; ++s) {
        #pragma unroll
        for (int t = 0; t < 8; ++t) {
            #pragma unroll
            for (int j = 0; j < 8; ++j) {
                int k = s * 32 + kg * 8 + j;
                bf[t][s][j] = f2bf(W[k * HC + t * 16 + m]);
            }
        }
        #pragma unroll
        for (int j = 0; j < 8; ++j) {
            int k = s * 32 + kg * 8 + j;
            bf[8][s][j] = f2bf(sh[k * 16 + m]);
        }
    }

    int rowc = min(rowbase + m, n - 1);
    const float* xp = x + (long long)rowc * IN_CH + kg * 8;
    short8 af[2];
    #pragma unroll
    for (int s = 0; s < 2; ++s) {
        float4 f0 = *(const float4*)(xp + s * 32);
        float4 f1 = *(const float4*)(xp + s * 32 + 4);
        af[s][0] = f2bf(f0.x); af[s][1] = f2bf(f0.y);
        af[s][2] = f2bf(f0.z); af[s][3] = f2bf(f0.w);
        af[s][4] = f2bf(f1.x); af[s][5] = f2bf(f1.y);
        af[s][6] = f2bf(f1.z); af[s][7] = f2bf(f1.w);
    }

    f32x4 acc[9];
    #pragma unroll
    for (int t = 0; t < 9; ++t) acc[t] = (f32x4){0.f, 0.f, 0.f, 0.f};

    #pragma unroll
    for (int s = 0; s < 2; ++s)
        #pragma unroll
        for (int t = 0; t < 9; ++t)
            acc[t] = __builtin_amdgcn_mfma_f32_16x16x32_bf16(
                         af[s], bf[t][s], acc[t], 0, 0, 0);

    #pragma unroll
    for (int r = 0; r < 4; ++r) {
        int orow = rowbase + kg * 4 + r;
        if (orow < n) {
            __hip_bfloat16* hp = hb + (long long)orow * HC + m;
            #pragma unroll
            for (int t = 0; t < 8; ++t)
                hp[t * 16] = __float2bfloat16(acc[t][r]);
            float av = acc[8][r];
            if (m < 8) asrc[orow * HEADS + m] = av;
            else       adst[orow * HEADS + (m - 8)] = av;
        }
    }
}

// ---- fused softmax + aggregation: own-head exp, unroll-8 (87.3us floor,
// untouched) ----
__global__ __launch_bounds__(256) void agg_kernel(
    const int* __restrict__ csr, const int2* __restrict__ row2,
    const float* __restrict__ asrc, const float* __restrict__ adst,
    const __hip_bfloat16* __restrict__ hb, const float* __restrict__ bias,
    float* __restrict__ out, int n)
{
    int wave = threadIdx.x >> 6;
    int lane = threadIdx.x & 63;
    int d = blockIdx.x * 4 + wave;
    if (d >= n) return;

    int hO = lane >> 3;         // head owning this lane's output cols

    int2 se = row2[d];
    int start = se.x, end = se.y;

    float adstv = adst[d * HEADS + hO];
    const unsigned* hu = (const unsigned*)hb;

    // self loop
    float w = __expf(lrelu(asrc[d * HEADS + hO] + adstv));
    unsigned u = hu[(long long)d * 64 + lane];
    float denom = w;
    float accx = w * __uint_as_float(u << 16);
    float accy = w * __uint_as_float(u & 0xFFFF0000u);

    int j = start;
    for (; j + 7 < end; j += 8) {
        int s0 = csr[j],     s1 = csr[j + 1], s2 = csr[j + 2], s3 = csr[j + 3];
        int s4 = csr[j + 4], s5 = csr[j + 5], s6 = csr[j + 6], s7 = csr[j + 7];
        float w0 = __expf(lrelu(asrc[s0 * HEADS + hO] + adstv));
        float w1 = __expf(lrelu(asrc[s1 * HEADS + hO] + adstv));
        float w2 = __expf(lrelu(asrc[s2 * HEADS + hO] + adstv));
        float w3 = __expf(lrelu(asrc[s3 * HEADS + hO] + adstv));
        float w4 = __expf(lrelu(asrc[s4 * HEADS + hO] + adstv));
        float w5 = __expf(lrelu(asrc[s5 * HEADS + hO] + adstv));
        float w6 = __expf(lrelu(asrc[s6 * HEADS + hO] + adstv));
        float w7 = __expf(lrelu(asrc[s7 * HEADS + hO] + adstv));
        unsigned u0 = hu[(long long)s0 * 64 + lane];
        unsigned u1 = hu[(long long)s1 * 64 + lane];
        unsigned u2 = hu[(long long)s2 * 64 + lane];
        unsigned u3 = hu[(long long)s3 * 64 + lane];
        unsigned u4 = hu[(long long)s4 * 64 + lane];
        unsigned u5 = hu[(long long)s5 * 64 + lane];
        unsigned u6 = hu[(long long)s6 * 64 + lane];
        unsigned u7 = hu[(long long)s7 * 64 + lane];
        denom += ((w0 + w1) + (w2 + w3)) + ((w4 + w5) + (w6 + w7));
        accx = fmaf(w0, __uint_as_float(u0 << 16), accx);
        accy = fmaf(w0, __uint_as_float(u0 & 0xFFFF0000u), accy);
        accx = fmaf(w1, __uint_as_float(u1 << 16), accx);
        accy = fmaf(w1, __uint_as_float(u1 & 0xFFFF0000u), accy);
        accx = fmaf(w2, __uint_as_float(u2 << 16), accx);
        accy = fmaf(w2, __uint_as_float(u2 & 0xFFFF0000u), accy);
        accx = fmaf(w3, __uint_as_float(u3 << 16), accx);
        accy = fmaf(w3, __uint_as_float(u3 & 0xFFFF0000u), accy);
        accx = fmaf(w4, __uint_as_float(u4 << 16), accx);
        accy = fmaf(w4, __uint_as_float(u4 & 0xFFFF0000u), accy);
        accx = fmaf(w5, __uint_as_float(u5 << 16), accx);
        accy = fmaf(w5, __uint_as_float(u5 & 0xFFFF0000u), accy);
        accx = fmaf(w6, __uint_as_float(u6 << 16), accx);
        accy = fmaf(w6, __uint_as_float(u6 & 0xFFFF0000u), accy);
        accx = fmaf(w7, __uint_as_float(u7 << 16), accx);
        accy = fmaf(w7, __uint_as_float(u7 & 0xFFFF0000u), accy);
    }
    for (; j + 3 < end; j += 4) {
        int s0 = csr[j], s1 = csr[j + 1], s2 = csr[j + 2], s3 = csr[j + 3];
        float w0 = __expf(lrelu(asrc[s0 * HEADS + hO] + adstv));
        float w1 = __expf(lrelu(asrc[s1 * HEADS + hO] + adstv));
        float w2 = __expf(lrelu(asrc[s2 * HEADS + hO] + adstv));
        float w3 = __expf(lrelu(asrc[s3 * HEADS + hO] + adstv));
        unsigned u0 = hu[(long long)s0 * 64 + lane];
        unsigned u1 = hu[(long long)s1 * 64 + lane];
        unsigned u2 = hu[(long long)s2 * 64 + lane];
        unsigned u3 = hu[(long long)s3 * 64 + lane];
        denom += (w0 + w1) + (w2 + w3);
        accx = fmaf(w0, __uint_as_float(u0 << 16), accx);
        accy = fmaf(w0, __uint_as_float(u0 & 0xFFFF0000u), accy);
        accx = fmaf(w1, __uint_as_float(u1 << 16), accx);
        accy = fmaf(w1, __uint_as_float(u1 & 0xFFFF0000u), accy);
        accx = fmaf(w2, __uint_as_float(u2 << 16), accx);
        accy = fmaf(w2, __uint_as_float(u2 & 0xFFFF0000u), accy);
        accx = fmaf(w3, __uint_as_float(u3 << 16), accx);
        accy = fmaf(w3, __uint_as_float(u3 & 0xFFFF0000u), accy);
    }
    for (; j < end; ++j) {
        int s0 = csr[j];
        float w0 = __expf(lrelu(asrc[s0 * HEADS + hO] + adstv));
        unsigned u0 = hu[(long long)s0 * 64 + lane];
        denom += w0;
        accx = fmaf(w0, __uint_as_float(u0 << 16), accx);
        accy = fmaf(w0, __uint_as_float(u0 & 0xFFFF0000u), accy);
    }

    float inv = 1.f / (denom + 1e-16f);
    const float2* b2 = (const float2*)bias;
    float2 bb = b2[lane];
    float2 o;
    o.x = fmaxf(fmaf(accx, inv, bb.x), 0.f);
    o.y = fmaxf(fmaf(accy, inv, bb.y), 0.f);
    ((float2*)out)[(long long)d * 64 + lane] = o;
}

extern "C" void kernel_launch(void* const* d_in, const int* in_sizes, int n_in,
                              void* d_out, int out_size, void* d_ws, size_t ws_size,
                              hipStream_t stream) {
    const float* x       = (const float*)d_in[0];
    const float* W       = (const float*)d_in[1];
    const float* att_src = (const float*)d_in[2];
    const float* att_dst = (const float*)d_in[3];
    const float* bias    = (const float*)d_in[4];
    const int*   ei      = (const int*)d_in[5];

    int n = in_sizes[0] / IN_CH;        // 100000
    int E = in_sizes[5] / 2;            // 1600000
    float* out = (float*)d_out;
    int nbuck = (n + BK_SIZE - 1) >> BK_BITS;   // 391 (<=512 required)

    // workspace layout
    char* ws = (char*)d_ws;
    __hip_bfloat16* hb = (__hip_bfloat16*)ws; ws += (size_t)n * HC * 2;  // 25.6 MB
    float* asrc = (float*)ws;   ws += (size_t)n * HEADS * 4;             // 3.2 MB
    float* adst = (float*)ws;   ws += (size_t)n * HEADS * 4;             // 3.2 MB
    int*   csr  = (int*)ws;     ws += ((size_t)nbuck * BK_CAP + 64) * 4; // 8.0 MB
    unsigned* binned = (unsigned*)ws; ws += (size_t)nbuck * BK_CAP * 4;  // 8.0 MB
    int2*  row2 = (int2*)ws;    ws += (size_t)n * 8;                     // 0.8 MB
    int*   cursor=(int*)ws;     ws += 512 * 4;

    hipMemsetAsync(cursor, 0, 512 * 4, stream);

    int nbin = (E + BIN_CHUNK - 1) / BIN_CHUNK;     // 391
    bin_kernel<<<nbin, 256, 0, stream>>>(ei, E, nbuck, cursor, binned);

    int pblk = (n + 63) / 64;                       // 1563
    fused_proj_b4<<<nbuck + pblk, 256, 0, stream>>>(
        x, W, att_src, att_dst, hb, asrc, adst, n,
        binned, cursor, row2, csr, nbuck);

    int ablk = (n + 3) / 4;
    agg_kernel<<<ablk, 256, 0, stream>>>(csr, row2, asrc, adst, hb, bias, out, n);
}